// Round 1
// baseline (3027.843 us; speedup 1.0000x reference)
//
#include <hip/hip_runtime.h>
#include <hip/hip_bf16.h>

#define B_SZ   2
#define T_SEQ  2048
#define DMODEL 1024
#define NH     16
#define DH     64
#define NTOK   (B_SZ * T_SEQ)   // 4096

typedef unsigned short u16;
typedef short s16x8 __attribute__((ext_vector_type(8)));   // 8 bf16 as raw bits (4 VGPRs)
typedef unsigned short u16x8 __attribute__((ext_vector_type(8)));
typedef float f32x4 __attribute__((ext_vector_type(4)));

__device__ __forceinline__ u16 f2bf(float f) {
  unsigned u = __float_as_uint(f);
  u += 0x7FFFu + ((u >> 16) & 1u);   // round-to-nearest-even
  return (u16)(u >> 16);
}

// ---------------- cast fp32 -> bf16 (vectorized x4) ----------------
__global__ void cast_to_bf16(const float* __restrict__ in, u16* __restrict__ out, int n4) {
  int i = blockIdx.x * blockDim.x + threadIdx.x;
  if (i >= n4) return;
  float4 v = reinterpret_cast<const float4*>(in)[i];
  ushort4 r;
  r.x = f2bf(v.x); r.y = f2bf(v.y); r.z = f2bf(v.z); r.w = f2bf(v.w);
  reinterpret_cast<ushort4*>(out)[i] = r;
}

// ---------------- bf16 MFMA GEMM: C[M,N] = A[M,K] * B[N,K]^T ----------------
// 64x64 block tile, BK=32, 256 threads = 4 waves, wave w owns rows [16w,16w+16) x all 64 cols.
// EPI=0: scatter into QKV[3][B][H][T][D] fp32.  EPI=1: plain row-major fp32.
template <int EPI>
__global__ __launch_bounds__(256) void gemm_bf16_nt(
    const u16* __restrict__ A, const u16* __restrict__ Bm,
    int M, int N, int K,
    float* __restrict__ outQKV, float* __restrict__ outC) {
  __shared__ __align__(16) u16 As[64][40];   // +8 pad: row stride 80B keeps 16B align, 2-way banks (free)
  __shared__ __align__(16) u16 Bs[64][40];
  const int tid  = threadIdx.x;
  const int wave = tid >> 6;
  const int lane = tid & 63;
  const int bm = blockIdx.x * 64;
  const int bn = blockIdx.y * 64;

  f32x4 acc[4] = {};

  const int sr = tid >> 2;          // staging row 0..63
  const int sk = (tid & 3) * 8;     // staging k-offset {0,8,16,24}
  const u16* Ap = A  + (size_t)(bm + sr) * K + sk;
  const u16* Bp = Bm + (size_t)(bn + sr) * K + sk;

  const int frow = lane & 15;         // A: row m, B: col n
  const int ko   = (lane >> 4) * 8;   // k-offset within 32

  for (int k0 = 0; k0 < K; k0 += 32) {
    u16x8 av = *reinterpret_cast<const u16x8*>(Ap + k0);
    u16x8 bv = *reinterpret_cast<const u16x8*>(Bp + k0);
    *reinterpret_cast<u16x8*>(&As[sr][sk]) = av;
    *reinterpret_cast<u16x8*>(&Bs[sr][sk]) = bv;
    __syncthreads();
    s16x8 af = *reinterpret_cast<const s16x8*>(&As[wave * 16 + frow][ko]);
#pragma unroll
    for (int nt = 0; nt < 4; nt++) {
      s16x8 bf = *reinterpret_cast<const s16x8*>(&Bs[nt * 16 + frow][ko]);
      acc[nt] = __builtin_amdgcn_mfma_f32_16x16x32_bf16(af, bf, acc[nt], 0, 0, 0);
    }
    __syncthreads();
  }

  const int col = lane & 15;
  const int rb  = (lane >> 4) * 4;
#pragma unroll
  for (int nt = 0; nt < 4; nt++) {
#pragma unroll
    for (int r = 0; r < 4; r++) {
      int gm = bm + wave * 16 + rb + r;
      int gn = bn + nt * 16 + col;
      float v = acc[nt][r];
      if (EPI == 0) {
        int b = gm >> 11, t = gm & 2047;            // token -> (b,t)
        int which = gn >> 10, rem = gn & 1023;      // f -> (which,h,d)
        int h = rem >> 6, d = rem & 63;
        size_t idx = ((((size_t)which * B_SZ + b) * NH + h) * T_SEQ + t) * DH + d;
        outQKV[idx] = v;
      } else {
        outC[(size_t)gm * N + gn] = v;
      }
    }
  }
}

// ---------------- attention pass A: flash AV + (m,l) stats ----------------
// block = 256 thr, 32 q-rows; thread t: q-row = t/8, j-block/d-block = (t%8)*8
__global__ __launch_bounds__(256) void attn_pass_a(
    const float* __restrict__ Q, const float* __restrict__ Kg, const float* __restrict__ Vg,
    float* __restrict__ AV, float* __restrict__ Mrow, float* __restrict__ Lrow) {
  __shared__ float Qs[32][65];   // stride 65: all hot patterns <=2-way bank aliasing
  __shared__ float Ks[64][65];
  __shared__ float Vs[64][65];
  __shared__ float Ps[32][65];
  const int bh = blockIdx.y;
  const int q0 = (gridDim.x - 1 - blockIdx.x) * 32;   // heavy blocks first
  const int tid = threadIdx.x;
  const size_t base = (size_t)bh * T_SEQ * DH;
  const float* Qp = Q  + base + (size_t)q0 * DH;
  const float* Kp = Kg + base;
  const float* Vp = Vg + base;

#pragma unroll
  for (int p = 0; p < 2; p++) {   // stage Q tile 32x64
    int flat = p * 1024 + tid * 4;
    int r = flat >> 6, c = flat & 63;
    float4 qv = *reinterpret_cast<const float4*>(Qp + flat);
    Qs[r][c] = qv.x; Qs[r][c + 1] = qv.y; Qs[r][c + 2] = qv.z; Qs[r][c + 3] = qv.w;
  }

  const int qr = tid >> 3;
  const int jb = (tid & 7) * 8;
  const int dcol = jb;
  const int qglob = q0 + qr;
  float m_r = -1e30f, l_r = 0.0f;
  float O[8];
#pragma unroll
  for (int i = 0; i < 8; i++) O[i] = 0.0f;

  const int ntile = (q0 + 32 + 63) >> 6;
  for (int ti = 0; ti < ntile; ti++) {
    const int j0 = ti * 64;
#pragma unroll
    for (int p = 0; p < 4; p++) {   // stage K,V tiles 64x64 (coalesced 16B/lane)
      int flat = p * 1024 + tid * 4;
      int r = flat >> 6, c = flat & 63;
      float4 kv = *reinterpret_cast<const float4*>(Kp + (size_t)j0 * DH + flat);
      float4 vv = *reinterpret_cast<const float4*>(Vp + (size_t)j0 * DH + flat);
      Ks[r][c] = kv.x; Ks[r][c + 1] = kv.y; Ks[r][c + 2] = kv.z; Ks[r][c + 3] = kv.w;
      Vs[r][c] = vv.x; Vs[r][c + 1] = vv.y; Vs[r][c + 2] = vv.z; Vs[r][c + 3] = vv.w;
    }
    __syncthreads();

    float s[8];
#pragma unroll
    for (int jj = 0; jj < 8; jj++) s[jj] = 0.0f;
    for (int d = 0; d < 64; d++) {
      float qv = Qs[qr][d];
#pragma unroll
      for (int jj = 0; jj < 8; jj++) s[jj] = fmaf(qv, Ks[jb + jj][d], s[jj]);
    }
    float tmax = -1e30f;
#pragma unroll
    for (int jj = 0; jj < 8; jj++) {
      int j = j0 + jb + jj;
      s[jj] = (j <= qglob) ? s[jj] * 0.125f : -1e30f;
      tmax = fmaxf(tmax, s[jj]);
    }
#pragma unroll
    for (int off = 1; off < 8; off <<= 1) tmax = fmaxf(tmax, __shfl_xor(tmax, off));
    const float m_new = fmaxf(m_r, tmax);
    const float alpha = __expf(m_r - m_new);
    float p_sum = 0.0f;
    float pw[8];
#pragma unroll
    for (int jj = 0; jj < 8; jj++) { pw[jj] = __expf(s[jj] - m_new); p_sum += pw[jj]; }
#pragma unroll
    for (int off = 1; off < 8; off <<= 1) p_sum += __shfl_xor(p_sum, off);
    l_r = l_r * alpha + p_sum;
    m_r = m_new;
#pragma unroll
    for (int jj = 0; jj < 8; jj++) Ps[qr][jb + jj] = pw[jj];
#pragma unroll
    for (int i = 0; i < 8; i++) O[i] *= alpha;
    __syncthreads();
    for (int j = 0; j < 64; j++) {
      float p = Ps[qr][j];
#pragma unroll
      for (int i = 0; i < 8; i++) O[i] = fmaf(p, Vs[j][dcol + i], O[i]);
    }
    __syncthreads();
  }

  const float inv_l = 1.0f / l_r;
  float* dst = AV + base + (size_t)qglob * DH + dcol;
#pragma unroll
  for (int i = 0; i < 8; i++) dst[i] = O[i] * inv_l;
  if ((tid & 7) == 0) {
    Mrow[bh * T_SEQ + qglob] = m_r;
    Lrow[bh * T_SEQ + qglob] = l_r;
  }
}

// ---------------- attention pass B: AAV = A*AV with stored (m,l); fuse tw = 2AV - AAV -> bf16 ----------------
__global__ __launch_bounds__(256) void attn_pass_b(
    const float* __restrict__ Q, const float* __restrict__ Kg, const float* __restrict__ AVg,
    const float* __restrict__ Mrow, const float* __restrict__ Lrow,
    u16* __restrict__ TW) {
  __shared__ float Qs[32][65];
  __shared__ float Ks[64][65];
  __shared__ float Vs[64][65];
  __shared__ float Ps[32][65];
  const int bh = blockIdx.y;
  const int q0 = (gridDim.x - 1 - blockIdx.x) * 32;
  const int tid = threadIdx.x;
  const size_t base = (size_t)bh * T_SEQ * DH;
  const float* Qp = Q   + base + (size_t)q0 * DH;
  const float* Kp = Kg  + base;
  const float* Vp = AVg + base;

#pragma unroll
  for (int p = 0; p < 2; p++) {
    int flat = p * 1024 + tid * 4;
    int r = flat >> 6, c = flat & 63;
    float4 qv = *reinterpret_cast<const float4*>(Qp + flat);
    Qs[r][c] = qv.x; Qs[r][c + 1] = qv.y; Qs[r][c + 2] = qv.z; Qs[r][c + 3] = qv.w;
  }

  const int qr = tid >> 3;
  const int jb = (tid & 7) * 8;
  const int dcol = jb;
  const int qglob = q0 + qr;
  const float m_r   = Mrow[bh * T_SEQ + qglob];
  const float inv_l = 1.0f / Lrow[bh * T_SEQ + qglob];
  float O[8];
#pragma unroll
  for (int i = 0; i < 8; i++) O[i] = 0.0f;

  const int ntile = (q0 + 32 + 63) >> 6;
  for (int ti = 0; ti < ntile; ti++) {
    const int j0 = ti * 64;
#pragma unroll
    for (int p = 0; p < 4; p++) {
      int flat = p * 1024 + tid * 4;
      int r = flat >> 6, c = flat & 63;
      float4 kv = *reinterpret_cast<const float4*>(Kp + (size_t)j0 * DH + flat);
      float4 vv = *reinterpret_cast<const float4*>(Vp + (size_t)j0 * DH + flat);
      Ks[r][c] = kv.x; Ks[r][c + 1] = kv.y; Ks[r][c + 2] = kv.z; Ks[r][c + 3] = kv.w;
      Vs[r][c] = vv.x; Vs[r][c + 1] = vv.y; Vs[r][c + 2] = vv.z; Vs[r][c + 3] = vv.w;
    }
    __syncthreads();

    float s[8];
#pragma unroll
    for (int jj = 0; jj < 8; jj++) s[jj] = 0.0f;
    for (int d = 0; d < 64; d++) {
      float qv = Qs[qr][d];
#pragma unroll
      for (int jj = 0; jj < 8; jj++) s[jj] = fmaf(qv, Ks[jb + jj][d], s[jj]);
    }
#pragma unroll
    for (int jj = 0; jj < 8; jj++) {
      int j = j0 + jb + jj;
      Ps[qr][jb + jj] = (j <= qglob) ? __expf(s[jj] * 0.125f - m_r) : 0.0f;
    }
    __syncthreads();
    for (int j = 0; j < 64; j++) {
      float p = Ps[qr][j];
#pragma unroll
      for (int i = 0; i < 8; i++) O[i] = fmaf(p, Vs[j][dcol + i], O[i]);
    }
    __syncthreads();
  }

  const int b = bh >> 4, h = bh & 15;
  const size_t tok = (size_t)b * T_SEQ + qglob;
  const float* avp = AVg + base + (size_t)qglob * DH + dcol;
  u16* twp = TW + tok * DMODEL + h * DH + dcol;
#pragma unroll
  for (int i = 0; i < 8; i++) {
    float aav = O[i] * inv_l;
    twp[i] = f2bf(2.0f * avp[i] - aav);
  }
}

// ---------------- launch ----------------
extern "C" void kernel_launch(void* const* d_in, const int* in_sizes, int n_in,
                              void* d_out, int out_size, void* d_ws, size_t ws_size,
                              hipStream_t stream) {
  const float* x    = (const float*)d_in[0];
  const float* Wqkv = (const float*)d_in[1];
  const float* Wout = (const float*)d_in[2];
  float* out = (float*)d_out;
  char* ws = (char*)d_ws;

  // ws layout (bytes)
  u16*   Xb    = (u16*)(ws + 0);           //  8,388,608  (4096x1024 bf16)
  u16*   Wqkvb = (u16*)(ws + 8388608);     //  6,291,456  (3072x1024 bf16)
  u16*   Woutb = (u16*)(ws + 14680064);    //  2,097,152  (1024x1024 bf16)
  float* QKV   = (float*)(ws + 16777216);  // 50,331,648  (3 x B x H x T x D fp32)
  float* AVb   = (float*)(ws + 67108864);  // 16,777,216
  float* Mrow  = (float*)(ws + 83886080);  //    262,144
  float* Lrow  = (float*)(ws + 84148224);  //    262,144
  u16*   TW    = (u16*)(ws + 84410368);    //  8,388,608  (4096x1024 bf16)

  cast_to_bf16<<<4096, 256, 0, stream>>>(x, Xb, 1048576);
  cast_to_bf16<<<3072, 256, 0, stream>>>(Wqkv, Wqkvb, 786432);
  cast_to_bf16<<<1024, 256, 0, stream>>>(Wout, Woutb, 262144);

  gemm_bf16_nt<0><<<dim3(64, 48), 256, 0, stream>>>(Xb, Wqkvb, NTOK, 3 * DMODEL, DMODEL, QKV, nullptr);

  const float* Qm = QKV;
  const float* Km = QKV + 4194304;
  const float* Vm = QKV + 8388608;
  attn_pass_a<<<dim3(64, 32), 256, 0, stream>>>(Qm, Km, Vm, AVb, Mrow, Lrow);
  attn_pass_b<<<dim3(64, 32), 256, 0, stream>>>(Qm, Km, AVb, Mrow, Lrow, TW);

  gemm_bf16_nt<1><<<dim3(64, 16), 256, 0, stream>>>(TW, Woutb, NTOK, DMODEL, DMODEL, nullptr, out);
}

// Round 2
// 322.636 us; speedup vs baseline: 9.3847x; 9.3847x over previous
//
#include <hip/hip_runtime.h>
#include <hip/hip_bf16.h>

#define T_SEQ  2048
#define DMODEL 1024
#define NH     16
#define DH     64
#define NTOK   4096

typedef unsigned short u16;
typedef short s16x8 __attribute__((ext_vector_type(8)));   // 8 bf16 raw bits (4 VGPRs)
typedef unsigned short u16x8 __attribute__((ext_vector_type(8)));
typedef float f32x4 __attribute__((ext_vector_type(4)));

__device__ __forceinline__ u16 f2bf(float f) {
  unsigned u = __float_as_uint(f);
  u += 0x7FFFu + ((u >> 16) & 1u);   // RNE
  return (u16)(u >> 16);
}

// ---------------- cast fp32 -> bf16 ----------------
__global__ void cast_to_bf16(const float* __restrict__ in, u16* __restrict__ out, int n4) {
  int i = blockIdx.x * blockDim.x + threadIdx.x;
  if (i >= n4) return;
  float4 v = reinterpret_cast<const float4*>(in)[i];
  ushort4 r;
  r.x = f2bf(v.x); r.y = f2bf(v.y); r.z = f2bf(v.z); r.w = f2bf(v.w);
  reinterpret_cast<ushort4*>(out)[i] = r;
}

// ---------------- bf16 MFMA GEMM: C[M,N] = A[M,K]*B[N,K]^T ----------------
// EPI=0: QK projection. N=2048, bn-tile = one (which,h); Q scaled by 0.125; bf16 out,
//        Qb/Kb layout [h][token(4096)][64], coalesced via Cs transpose-staging.
// EPI=1: row-major bf16 out (V^T: A=Wv M=1024 feats, B=X N=4096 tokens -> Vtb[f][token]).
// EPI=2: row-major fp32 out (final projection).
template <int EPI>
__global__ __launch_bounds__(256) void gemm_bf16_nt(
    const u16* __restrict__ A, const u16* __restrict__ Bm,
    int M, int N, int K,
    u16* __restrict__ outQ, u16* __restrict__ outK,
    u16* __restrict__ outT, float* __restrict__ outF) {
  __shared__ __align__(16) u16 As[64][40];
  __shared__ __align__(16) u16 Bs[64][40];
  __shared__ __align__(16) u16 Cs[64][72];
  const int tid  = threadIdx.x;
  const int wave = tid >> 6;
  const int lane = tid & 63;
  const int bm = blockIdx.x * 64;
  const int bn = blockIdx.y * 64;

  f32x4 acc[4] = {};

  const int sr = tid >> 2;
  const int sk = (tid & 3) * 8;
  const u16* Ap = A  + (size_t)(bm + sr) * K + sk;
  const u16* Bp = Bm + (size_t)(bn + sr) * K + sk;

  const int frow = lane & 15;
  const int ko   = (lane >> 4) * 8;

  for (int k0 = 0; k0 < K; k0 += 32) {
    u16x8 av = *reinterpret_cast<const u16x8*>(Ap + k0);
    u16x8 bv = *reinterpret_cast<const u16x8*>(Bp + k0);
    *reinterpret_cast<u16x8*>(&As[sr][sk]) = av;
    *reinterpret_cast<u16x8*>(&Bs[sr][sk]) = bv;
    __syncthreads();
    s16x8 af = *reinterpret_cast<const s16x8*>(&As[wave * 16 + frow][ko]);
#pragma unroll
    for (int nt = 0; nt < 4; nt++) {
      s16x8 bf = *reinterpret_cast<const s16x8*>(&Bs[nt * 16 + frow][ko]);
      acc[nt] = __builtin_amdgcn_mfma_f32_16x16x32_bf16(af, bf, acc[nt], 0, 0, 0);
    }
    __syncthreads();
  }

  const int col = lane & 15;
  const int rb  = (lane >> 4) * 4;
  if (EPI == 2) {
#pragma unroll
    for (int nt = 0; nt < 4; nt++)
#pragma unroll
      for (int r = 0; r < 4; r++)
        outF[(size_t)(bm + wave * 16 + rb + r) * N + bn + nt * 16 + col] = acc[nt][r];
    return;
  }
  const float scale = (EPI == 0 && bn < 1024) ? 0.125f : 1.0f;
#pragma unroll
  for (int nt = 0; nt < 4; nt++)
#pragma unroll
    for (int r = 0; r < 4; r++)
      Cs[wave * 16 + rb + r][nt * 16 + col] = f2bf(acc[nt][r] * scale);
  __syncthreads();
  const int row = tid >> 2;
  const int seg = (tid & 3) * 16;
  u16x8 v0 = *reinterpret_cast<const u16x8*>(&Cs[row][seg]);
  u16x8 v1 = *reinterpret_cast<const u16x8*>(&Cs[row][seg + 8]);
  if (EPI == 0) {
    const int which = bn >> 10;
    const int h = (bn >> 6) & 15;
    u16* dst = (which ? outK : outQ) + ((size_t)h * NTOK + bm + row) * 64 + seg;
    *reinterpret_cast<u16x8*>(dst) = v0;
    *reinterpret_cast<u16x8*>(dst + 8) = v1;
  } else {
    u16* dst = outT + (size_t)(bm + row) * N + bn + seg;
    *reinterpret_cast<u16x8*>(dst) = v0;
    *reinterpret_cast<u16x8*>(dst + 8) = v1;
  }
}

// ---------------- MFMA flash attention, pass A: AV + (m,l) ----------------
// grid (32 qtiles, 32 bh), 256 thr = 4 waves; wave w: q rows [64*qt+16w, +16).
// Qb/Kb [h][token][64] bf16 (Q pre-scaled); Vtb [h*64+d][token] bf16.
// Out: AVt [h*64+d][token] fp32; Mrow/Lrow [bh][2048] fp32.
__global__ __launch_bounds__(256, 4) void attn_pass_a(
    const u16* __restrict__ Qb, const u16* __restrict__ Kb, const u16* __restrict__ Vtb,
    float* __restrict__ AVt, float* __restrict__ Mrow, float* __restrict__ Lrow) {
  __shared__ __align__(16) u16 Qs[64][72];
  __shared__ __align__(16) u16 Ks[64][72];
  __shared__ __align__(16) u16 Vs[64][72];
  __shared__ __align__(16) u16 Ps[64][72];
  const int tid = threadIdx.x, wave = tid >> 6, lane = tid & 63;
  const int y = blockIdx.y, b = y >> 4, h = y & 15;
  const int qt = (31 - (int)blockIdx.x + y) & 31;   // balance heavy/light tiles per CU
  const int q0 = qt * 64;
  const size_t qk_base = ((size_t)h * NTOK + b * T_SEQ) * 64;
  const size_t vt_base = (size_t)h * 64 * NTOK + b * T_SEQ;

#pragma unroll
  for (int it = 0; it < 2; it++) {
    int flat = it * 2048 + tid * 8;
    int r = flat >> 6, c = flat & 63;
    *reinterpret_cast<u16x8*>(&Qs[r][c]) =
        *reinterpret_cast<const u16x8*>(Qb + qk_base + (size_t)(q0 + r) * 64 + c);
  }
  const int f15 = lane & 15;
  const int ko  = (lane >> 4) * 8;
  const int rb  = (lane >> 4) * 4;
  const int qrow0 = q0 + wave * 16 + rb;

  float m_run[4], l_run[4];
#pragma unroll
  for (int r = 0; r < 4; r++) { m_run[r] = -3.0e38f; l_run[r] = 0.0f; }
  f32x4 accO[4] = {};

  for (int ti = 0; ti <= qt; ti++) {
    const int j0 = ti * 64;
#pragma unroll
    for (int it = 0; it < 2; it++) {
      int flat = it * 2048 + tid * 8;
      int r = flat >> 6, c = flat & 63;
      *reinterpret_cast<u16x8*>(&Ks[r][c]) =
          *reinterpret_cast<const u16x8*>(Kb + qk_base + (size_t)(j0 + r) * 64 + c);
      *reinterpret_cast<u16x8*>(&Vs[r][c]) =
          *reinterpret_cast<const u16x8*>(Vtb + vt_base + (size_t)r * NTOK + j0 + c);
    }
    __syncthreads();

    f32x4 accS[4] = {};
#pragma unroll
    for (int ks = 0; ks < 2; ks++) {
      s16x8 aq = *reinterpret_cast<const s16x8*>(&Qs[wave * 16 + f15][ks * 32 + ko]);
#pragma unroll
      for (int nt = 0; nt < 4; nt++) {
        s16x8 bk = *reinterpret_cast<const s16x8*>(&Ks[nt * 16 + f15][ks * 32 + ko]);
        accS[nt] = __builtin_amdgcn_mfma_f32_16x16x32_bf16(aq, bk, accS[nt], 0, 0, 0);
      }
    }
    if (ti == qt) {
#pragma unroll
      for (int nt = 0; nt < 4; nt++)
#pragma unroll
        for (int r = 0; r < 4; r++)
          if (j0 + nt * 16 + f15 > qrow0 + r) accS[nt][r] = -3.0e38f;
    }
    float al[4];
#pragma unroll
    for (int r = 0; r < 4; r++) {
      float mx = fmaxf(fmaxf(accS[0][r], accS[1][r]), fmaxf(accS[2][r], accS[3][r]));
#pragma unroll
      for (int off = 1; off < 16; off <<= 1) mx = fmaxf(mx, __shfl_xor(mx, off));
      float mn = fmaxf(m_run[r], mx);
      al[r] = __expf(m_run[r] - mn);
      m_run[r] = mn;
    }
    float ls[4] = {0, 0, 0, 0};
    float pw[4][4];
#pragma unroll
    for (int nt = 0; nt < 4; nt++)
#pragma unroll
      for (int r = 0; r < 4; r++) {
        float p = __expf(accS[nt][r] - m_run[r]);
        pw[nt][r] = p; ls[r] += p;
      }
#pragma unroll
    for (int r = 0; r < 4; r++) {
#pragma unroll
      for (int off = 1; off < 16; off <<= 1) ls[r] += __shfl_xor(ls[r], off);
      l_run[r] = l_run[r] * al[r] + ls[r];
    }
#pragma unroll
    for (int nt = 0; nt < 4; nt++)
#pragma unroll
      for (int r = 0; r < 4; r++) {
        accO[nt][r] *= al[r];
        Ps[wave * 16 + rb + r][nt * 16 + f15] = f2bf(pw[nt][r]);
      }
    __syncthreads();
#pragma unroll
    for (int ks = 0; ks < 2; ks++) {
      s16x8 ap = *reinterpret_cast<const s16x8*>(&Ps[wave * 16 + f15][ks * 32 + ko]);
#pragma unroll
      for (int nt = 0; nt < 4; nt++) {
        s16x8 bv = *reinterpret_cast<const s16x8*>(&Vs[nt * 16 + f15][ks * 32 + ko]);
        accO[nt] = __builtin_amdgcn_mfma_f32_16x16x32_bf16(ap, bv, accO[nt], 0, 0, 0);
      }
    }
    __syncthreads();
  }

  float invl[4];
#pragma unroll
  for (int r = 0; r < 4; r++) invl[r] = 1.0f / l_run[r];
#pragma unroll
  for (int nt = 0; nt < 4; nt++) {
    float4 o;
    o.x = accO[nt][0] * invl[0];
    o.y = accO[nt][1] * invl[1];
    o.z = accO[nt][2] * invl[2];
    o.w = accO[nt][3] * invl[3];
    *reinterpret_cast<float4*>(AVt + (size_t)(h * 64 + nt * 16 + f15) * NTOK + b * T_SEQ + qrow0) = o;
  }
  if (f15 == 0) {
#pragma unroll
    for (int r = 0; r < 4; r++) {
      Mrow[(size_t)y * T_SEQ + qrow0 - q0 + q0 + r] = m_run[r];
      Lrow[(size_t)y * T_SEQ + qrow0 + r] = l_run[r];
    }
  }
}

// ---------------- MFMA flash attention, pass B: AAV; TW = bf16(2AV - AAV) ----------------
__global__ __launch_bounds__(256, 4) void attn_pass_b(
    const u16* __restrict__ Qb, const u16* __restrict__ Kb, const float* __restrict__ AVt,
    const float* __restrict__ Mrow, const float* __restrict__ Lrow,
    u16* __restrict__ TW) {
  __shared__ __align__(16) u16 Qs[64][72];
  __shared__ __align__(16) u16 Ks[64][72];
  __shared__ __align__(16) u16 Vs[64][72];
  __shared__ __align__(16) u16 Ps[64][72];
  const int tid = threadIdx.x, wave = tid >> 6, lane = tid & 63;
  const int y = blockIdx.y, b = y >> 4, h = y & 15;
  const int qt = (31 - (int)blockIdx.x + y) & 31;
  const int q0 = qt * 64;
  const size_t qk_base = ((size_t)h * NTOK + b * T_SEQ) * 64;
  const size_t av_base = (size_t)h * 64 * NTOK + b * T_SEQ;

#pragma unroll
  for (int it = 0; it < 2; it++) {
    int flat = it * 2048 + tid * 8;
    int r = flat >> 6, c = flat & 63;
    *reinterpret_cast<u16x8*>(&Qs[r][c]) =
        *reinterpret_cast<const u16x8*>(Qb + qk_base + (size_t)(q0 + r) * 64 + c);
  }
  const int f15 = lane & 15;
  const int ko  = (lane >> 4) * 8;
  const int rb  = (lane >> 4) * 4;
  const int qrow0 = q0 + wave * 16 + rb;

  float m_r[4], invl[4];
#pragma unroll
  for (int r = 0; r < 4; r++) {
    m_r[r]  = Mrow[(size_t)y * T_SEQ + qrow0 + r];
    invl[r] = 1.0f / Lrow[(size_t)y * T_SEQ + qrow0 + r];
  }
  f32x4 accO[4] = {};

  for (int ti = 0; ti <= qt; ti++) {
    const int j0 = ti * 64;
#pragma unroll
    for (int it = 0; it < 2; it++) {
      int flat = it * 2048 + tid * 8;
      int r = flat >> 6, c = flat & 63;
      *reinterpret_cast<u16x8*>(&Ks[r][c]) =
          *reinterpret_cast<const u16x8*>(Kb + qk_base + (size_t)(j0 + r) * 64 + c);
      const float* src = AVt + av_base + (size_t)r * NTOK + j0 + c;
      float4 a0 = *reinterpret_cast<const float4*>(src);
      float4 a1 = *reinterpret_cast<const float4*>(src + 4);
      u16x8 pk;
      pk[0] = f2bf(a0.x); pk[1] = f2bf(a0.y); pk[2] = f2bf(a0.z); pk[3] = f2bf(a0.w);
      pk[4] = f2bf(a1.x); pk[5] = f2bf(a1.y); pk[6] = f2bf(a1.z); pk[7] = f2bf(a1.w);
      *reinterpret_cast<u16x8*>(&Vs[r][c]) = pk;
    }
    __syncthreads();

    f32x4 accS[4] = {};
#pragma unroll
    for (int ks = 0; ks < 2; ks++) {
      s16x8 aq = *reinterpret_cast<const s16x8*>(&Qs[wave * 16 + f15][ks * 32 + ko]);
#pragma unroll
      for (int nt = 0; nt < 4; nt++) {
        s16x8 bk = *reinterpret_cast<const s16x8*>(&Ks[nt * 16 + f15][ks * 32 + ko]);
        accS[nt] = __builtin_amdgcn_mfma_f32_16x16x32_bf16(aq, bk, accS[nt], 0, 0, 0);
      }
    }
    if (ti == qt) {
#pragma unroll
      for (int nt = 0; nt < 4; nt++)
#pragma unroll
        for (int r = 0; r < 4; r++)
          if (j0 + nt * 16 + f15 > qrow0 + r) accS[nt][r] = -3.0e38f;
    }
#pragma unroll
    for (int nt = 0; nt < 4; nt++)
#pragma unroll
      for (int r = 0; r < 4; r++)
        Ps[wave * 16 + rb + r][nt * 16 + f15] = f2bf(__expf(accS[nt][r] - m_r[r]));
    __syncthreads();
#pragma unroll
    for (int ks = 0; ks < 2; ks++) {
      s16x8 ap = *reinterpret_cast<const s16x8*>(&Ps[wave * 16 + f15][ks * 32 + ko]);
#pragma unroll
      for (int nt = 0; nt < 4; nt++) {
        s16x8 bv = *reinterpret_cast<const s16x8*>(&Vs[nt * 16 + f15][ks * 32 + ko]);
        accO[nt] = __builtin_amdgcn_mfma_f32_16x16x32_bf16(ap, bv, accO[nt], 0, 0, 0);
      }
    }
    __syncthreads();
  }

  // epilogue: tw = 2*AV - AAV, staged through Ps for coalesced bf16 store
#pragma unroll
  for (int nt = 0; nt < 4; nt++) {
    float4 av = *reinterpret_cast<const float4*>(
        AVt + (size_t)(h * 64 + nt * 16 + f15) * NTOK + b * T_SEQ + qrow0);
    const float* avp = &av.x;
#pragma unroll
    for (int r = 0; r < 4; r++)
      Ps[wave * 16 + rb + r][nt * 16 + f15] = f2bf(2.0f * avp[r] - accO[nt][r] * invl[r]);
  }
  __syncthreads();
#pragma unroll
  for (int it = 0; it < 2; it++) {
    int flat = it * 2048 + tid * 8;
    int r = flat >> 6, c = flat & 63;
    *reinterpret_cast<u16x8*>(TW + (size_t)(b * T_SEQ + q0 + r) * DMODEL + h * 64 + c) =
        *reinterpret_cast<const u16x8*>(&Ps[r][c]);
  }
}

// ---------------- launch ----------------
extern "C" void kernel_launch(void* const* d_in, const int* in_sizes, int n_in,
                              void* d_out, int out_size, void* d_ws, size_t ws_size,
                              hipStream_t stream) {
  const float* x    = (const float*)d_in[0];
  const float* Wqkv = (const float*)d_in[1];
  const float* Wout = (const float*)d_in[2];
  float* out = (float*)d_out;
  char* ws = (char*)d_ws;

  u16*   Xb    = (u16*)(ws + 0);           //  8 MB  4096x1024 bf16
  u16*   Wqkvb = (u16*)(ws + 8388608);     //  6 MB  3072x1024 bf16
  u16*   Woutb = (u16*)(ws + 14680064);    //  2 MB  1024x1024 bf16
  u16*   Qb    = (u16*)(ws + 16777216);    //  8 MB  [h][token][64] (pre-scaled)
  u16*   Kb    = (u16*)(ws + 25165824);    //  8 MB  [h][token][64]
  u16*   Vtb   = (u16*)(ws + 33554432);    //  8 MB  [h*64+d][token]
  u16*   TW    = (u16*)(ws + 41943040);    //  8 MB  [token][1024]
  float* AVt   = (float*)(ws + 50331648);  // 16 MB  [h*64+d][token] fp32
  float* Mrow  = (float*)(ws + 67108864);  // 256 KB [bh][2048]
  float* Lrow  = (float*)(ws + 67371008);  // 256 KB

  cast_to_bf16<<<4096, 256, 0, stream>>>(x, Xb, 1048576);
  cast_to_bf16<<<3072, 256, 0, stream>>>(Wqkv, Wqkvb, 786432);
  cast_to_bf16<<<1024, 256, 0, stream>>>(Wout, Woutb, 262144);

  // QK projection: C[token][2048] -> Qb (scaled), Kb
  gemm_bf16_nt<0><<<dim3(64, 32), 256, 0, stream>>>(Xb, Wqkvb, NTOK, 2048, DMODEL,
                                                    Qb, Kb, nullptr, nullptr);
  // V^T projection: C[feat][token] = Wv * X^T -> Vtb
  gemm_bf16_nt<1><<<dim3(16, 64), 256, 0, stream>>>(Wqkvb + 2048 * 1024, Xb, 1024, NTOK, DMODEL,
                                                    nullptr, nullptr, Vtb, nullptr);

  attn_pass_a<<<dim3(32, 32), 256, 0, stream>>>(Qb, Kb, Vtb, AVt, Mrow, Lrow);
  attn_pass_b<<<dim3(32, 32), 256, 0, stream>>>(Qb, Kb, AVt, Mrow, Lrow, TW);

  // out = TW @ Wout^T (fp32 out)
  gemm_bf16_nt<2><<<dim3(64, 16), 256, 0, stream>>>(TW, Woutb, NTOK, DMODEL, DMODEL,
                                                    nullptr, nullptr, nullptr, out);
}

// Round 3
// 311.137 us; speedup vs baseline: 9.7316x; 1.0370x over previous
//
#include <hip/hip_runtime.h>
#include <hip/hip_bf16.h>

#define T_SEQ  2048
#define DMODEL 1024
#define NH     16
#define DH     64
#define NTOK   4096
// 0.125 * log2(e): fold softmax scale AND exp->exp2 conversion into Q
#define QSCALE 0.18033688011112042f

typedef unsigned short u16;
typedef short s16x8 __attribute__((ext_vector_type(8)));   // 8 bf16 raw bits (4 VGPRs)
typedef unsigned short u16x8 __attribute__((ext_vector_type(8)));
typedef float f32x4 __attribute__((ext_vector_type(4)));

__device__ __forceinline__ u16 f2bf(float f) {
  unsigned u = __float_as_uint(f);
  u += 0x7FFFu + ((u >> 16) & 1u);   // RNE
  return (u16)(u >> 16);
}
// pack 2 floats -> 2 bf16 in one dword (a = low/first element)
__device__ __forceinline__ unsigned pk2(float a, float b) {
  __hip_bfloat162 h = __float22bfloat162_rn(make_float2(a, b));
  unsigned u;
  __builtin_memcpy(&u, &h, 4);
  return u;
}
__device__ __forceinline__ float bf2f(u16 x) {
  return __uint_as_float(((unsigned)x) << 16);
}

// ---------------- cast fp32 -> bf16 ----------------
__global__ void cast_to_bf16(const float* __restrict__ in, u16* __restrict__ out, int n4) {
  int i = blockIdx.x * blockDim.x + threadIdx.x;
  if (i >= n4) return;
  float4 v = reinterpret_cast<const float4*>(in)[i];
  ushort4 r;
  r.x = f2bf(v.x); r.y = f2bf(v.y); r.z = f2bf(v.z); r.w = f2bf(v.w);
  reinterpret_cast<ushort4*>(out)[i] = r;
}

// ---------------- bf16 MFMA GEMM: C[M,N] = A[M,K]*B[N,K]^T (unchanged from R2) ----------------
template <int EPI>
__global__ __launch_bounds__(256) void gemm_bf16_nt(
    const u16* __restrict__ A, const u16* __restrict__ Bm,
    int M, int N, int K,
    u16* __restrict__ outQ, u16* __restrict__ outK,
    u16* __restrict__ outT, float* __restrict__ outF) {
  __shared__ __align__(16) u16 As[64][40];
  __shared__ __align__(16) u16 Bs[64][40];
  __shared__ __align__(16) u16 Cs[64][72];
  const int tid  = threadIdx.x;
  const int wave = tid >> 6;
  const int lane = tid & 63;
  const int bm = blockIdx.x * 64;
  const int bn = blockIdx.y * 64;

  f32x4 acc[4] = {};

  const int sr = tid >> 2;
  const int sk = (tid & 3) * 8;
  const u16* Ap = A  + (size_t)(bm + sr) * K + sk;
  const u16* Bp = Bm + (size_t)(bn + sr) * K + sk;

  const int frow = lane & 15;
  const int ko   = (lane >> 4) * 8;

  for (int k0 = 0; k0 < K; k0 += 32) {
    u16x8 av = *reinterpret_cast<const u16x8*>(Ap + k0);
    u16x8 bv = *reinterpret_cast<const u16x8*>(Bp + k0);
    *reinterpret_cast<u16x8*>(&As[sr][sk]) = av;
    *reinterpret_cast<u16x8*>(&Bs[sr][sk]) = bv;
    __syncthreads();
    s16x8 af = *reinterpret_cast<const s16x8*>(&As[wave * 16 + frow][ko]);
#pragma unroll
    for (int nt = 0; nt < 4; nt++) {
      s16x8 bf = *reinterpret_cast<const s16x8*>(&Bs[nt * 16 + frow][ko]);
      acc[nt] = __builtin_amdgcn_mfma_f32_16x16x32_bf16(af, bf, acc[nt], 0, 0, 0);
    }
    __syncthreads();
  }

  const int col = lane & 15;
  const int rb  = (lane >> 4) * 4;
  if (EPI == 2) {
#pragma unroll
    for (int nt = 0; nt < 4; nt++)
#pragma unroll
      for (int r = 0; r < 4; r++)
        outF[(size_t)(bm + wave * 16 + rb + r) * N + bn + nt * 16 + col] = acc[nt][r];
    return;
  }
  const float scale = (EPI == 0 && bn < 1024) ? QSCALE : 1.0f;
#pragma unroll
  for (int nt = 0; nt < 4; nt++)
#pragma unroll
    for (int r = 0; r < 4; r++)
      Cs[wave * 16 + rb + r][nt * 16 + col] = f2bf(acc[nt][r] * scale);
  __syncthreads();
  const int row = tid >> 2;
  const int seg = (tid & 3) * 16;
  u16x8 v0 = *reinterpret_cast<const u16x8*>(&Cs[row][seg]);
  u16x8 v1 = *reinterpret_cast<const u16x8*>(&Cs[row][seg + 8]);
  if (EPI == 0) {
    const int which = bn >> 10;
    const int h = (bn >> 6) & 15;
    u16* dst = (which ? outK : outQ) + ((size_t)h * NTOK + bm + row) * 64 + seg;
    *reinterpret_cast<u16x8*>(dst) = v0;
    *reinterpret_cast<u16x8*>(dst + 8) = v1;
  } else {
    u16* dst = outT + (size_t)(bm + row) * N + bn + seg;
    *reinterpret_cast<u16x8*>(dst) = v0;
    *reinterpret_cast<u16x8*>(dst + 8) = v1;
  }
}

// ---------------- transposed MFMA flash attention ----------------
// S^T = K·Q^T  (D[j][q], col=q=lane&15 -> softmax state fully in-lane)
// O^T = V^T·P  (D[d][q], col=q -> alpha rescale in-lane)
// P written [q][j] with packed b64 (same-wave region -> no barrier); 2 barriers/iter.
// Qb/Kb [h][token][64] bf16 (Q pre-scaled by 0.125*log2e); Vtb [h*64+d][token] bf16.
// pass A out: AVt bf16 [h*64+d][tok], AVq bf16 [tok][dmodel], Mrow/Lrow (log2 domain).
__global__ __launch_bounds__(256) void attn_pass_a(
    const u16* __restrict__ Qb, const u16* __restrict__ Kb, const u16* __restrict__ Vtb,
    u16* __restrict__ AVt, u16* __restrict__ AVq,
    float* __restrict__ Mrow, float* __restrict__ Lrow) {
  __shared__ __align__(16) u16 Ks[64][72];
  __shared__ __align__(16) u16 Vs[64][72];
  __shared__ __align__(16) u16 Ps[64][72];
  const int tid = threadIdx.x, wave = tid >> 6, lane = tid & 63;
  const int f15 = lane & 15, quad = lane >> 4;
  const int y = blockIdx.y, b = y >> 4, h = y & 15;
  const int qt = (31 - (int)blockIdx.x + y) & 31;   // load-balance swizzle
  const int q0 = qt * 64;
  const size_t qk_base = ((size_t)h * NTOK + b * T_SEQ) * 64;
  const size_t vt_base = (size_t)h * 64 * NTOK + (size_t)b * T_SEQ;

  const int qrow = q0 + wave * 16 + f15;   // this lane's q (all its S/O columns)
  // Q fragments in registers (B-operand role): k = quad*8 + ks*32 + 0..7
  s16x8 qf0, qf1;
  {
    const u16* qp = Qb + qk_base + (size_t)qrow * 64 + quad * 8;
    qf0 = *reinterpret_cast<const s16x8*>(qp);
    qf1 = *reinterpret_cast<const s16x8*>(qp + 32);
  }
  float m_run = -3.0e38f, l_run = 0.0f;
  f32x4 accO[4] = {};

  const int s_r = tid >> 3;          // staging row 0..31 (+32)
  const int s_c = (tid & 7) * 8;

  for (int ti = 0; ti <= qt; ti++) {
    const int j0 = ti * 64;
#pragma unroll
    for (int it = 0; it < 2; it++) {
      int r = it * 32 + s_r;
      *reinterpret_cast<u16x8*>(&Ks[r][s_c]) =
          *reinterpret_cast<const u16x8*>(Kb + qk_base + (size_t)(j0 + r) * 64 + s_c);
      *reinterpret_cast<u16x8*>(&Vs[r][s_c]) =
          *reinterpret_cast<const u16x8*>(Vtb + vt_base + (size_t)r * NTOK + j0 + s_c);
    }
    __syncthreads();

    // S^T: A = K rows (j), B = Q regs (q)
    f32x4 accS[4] = {};
#pragma unroll
    for (int nt = 0; nt < 4; nt++) {
      s16x8 ak0 = *reinterpret_cast<const s16x8*>(&Ks[nt * 16 + f15][quad * 8]);
      accS[nt] = __builtin_amdgcn_mfma_f32_16x16x32_bf16(ak0, qf0, accS[nt], 0, 0, 0);
      s16x8 ak1 = *reinterpret_cast<const s16x8*>(&Ks[nt * 16 + f15][32 + quad * 8]);
      accS[nt] = __builtin_amdgcn_mfma_f32_16x16x32_bf16(ak1, qf1, accS[nt], 0, 0, 0);
    }
    if (ti == qt) {   // causal mask on diagonal tile: j = j0+nt*16+quad*4+r
#pragma unroll
      for (int nt = 0; nt < 4; nt++)
#pragma unroll
        for (int r = 0; r < 4; r++)
          if (j0 + nt * 16 + quad * 4 + r > qrow) accS[nt][r] = -3.0e38f;
    }
    // in-lane softmax over 16 j-values + 2 cross-quad shuffles
    float mx = fmaxf(fmaxf(accS[0][0], accS[0][1]), fmaxf(accS[0][2], accS[0][3]));
#pragma unroll
    for (int nt = 1; nt < 4; nt++)
      mx = fmaxf(mx, fmaxf(fmaxf(accS[nt][0], accS[nt][1]), fmaxf(accS[nt][2], accS[nt][3])));
    mx = fmaxf(mx, __shfl_xor(mx, 16));
    mx = fmaxf(mx, __shfl_xor(mx, 32));
    const float m_new = fmaxf(m_run, mx);
    const float alpha = __builtin_amdgcn_exp2f(m_run - m_new);
    float ls = 0.0f;
#pragma unroll
    for (int nt = 0; nt < 4; nt++) {
      float p0 = __builtin_amdgcn_exp2f(accS[nt][0] - m_new);
      float p1 = __builtin_amdgcn_exp2f(accS[nt][1] - m_new);
      float p2 = __builtin_amdgcn_exp2f(accS[nt][2] - m_new);
      float p3 = __builtin_amdgcn_exp2f(accS[nt][3] - m_new);
      ls += (p0 + p1) + (p2 + p3);
      uint2 w; w.x = pk2(p0, p1); w.y = pk2(p2, p3);
      *reinterpret_cast<uint2*>(&Ps[wave * 16 + f15][nt * 16 + quad * 4]) = w;
#pragma unroll
      for (int r = 0; r < 4; r++) accO[nt][r] *= alpha;
    }
    ls += __shfl_xor(ls, 16);
    ls += __shfl_xor(ls, 32);
    l_run = l_run * alpha + ls;
    m_run = m_new;
    // O^T: A = V^T rows (d), B = P rows (q) — same-wave Ps, no barrier needed
#pragma unroll
    for (int ks = 0; ks < 2; ks++) {
      s16x8 bp = *reinterpret_cast<const s16x8*>(&Ps[wave * 16 + f15][ks * 32 + quad * 8]);
#pragma unroll
      for (int nt = 0; nt < 4; nt++) {
        s16x8 av = *reinterpret_cast<const s16x8*>(&Vs[nt * 16 + f15][ks * 32 + quad * 8]);
        accO[nt] = __builtin_amdgcn_mfma_f32_16x16x32_bf16(av, bp, accO[nt], 0, 0, 0);
      }
    }
    __syncthreads();
  }

  const float invl = 1.0f / l_run;
  // stage AV tile both ways: Ks = [d][q] (for AVt), Vs = [q][d] (for AVq)
#pragma unroll
  for (int nt = 0; nt < 4; nt++) {
    float v0 = accO[nt][0] * invl, v1 = accO[nt][1] * invl;
    float v2 = accO[nt][2] * invl, v3 = accO[nt][3] * invl;
    Ks[nt * 16 + quad * 4 + 0][wave * 16 + f15] = f2bf(v0);
    Ks[nt * 16 + quad * 4 + 1][wave * 16 + f15] = f2bf(v1);
    Ks[nt * 16 + quad * 4 + 2][wave * 16 + f15] = f2bf(v2);
    Ks[nt * 16 + quad * 4 + 3][wave * 16 + f15] = f2bf(v3);
    uint2 w; w.x = pk2(v0, v1); w.y = pk2(v2, v3);
    *reinterpret_cast<uint2*>(&Vs[wave * 16 + f15][nt * 16 + quad * 4]) = w;
  }
  __syncthreads();
#pragma unroll
  for (int it = 0; it < 2; it++) {
    int r = it * 32 + s_r;
    *reinterpret_cast<u16x8*>(AVt + vt_base + (size_t)r * NTOK + q0 + s_c) =
        *reinterpret_cast<const u16x8*>(&Ks[r][s_c]);
    *reinterpret_cast<u16x8*>(AVq + (size_t)(b * T_SEQ + q0 + r) * DMODEL + h * 64 + s_c) =
        *reinterpret_cast<const u16x8*>(&Vs[r][s_c]);
  }
  if (quad == 0) {
    Mrow[(size_t)y * T_SEQ + qrow] = m_run;
    Lrow[(size_t)y * T_SEQ + qrow] = l_run;
  }
}

// pass B: AAV^T with stored (m,l); epilogue tw = bf16(2*AV - AAV) -> TW[tok][dmodel]
__global__ __launch_bounds__(256) void attn_pass_b(
    const u16* __restrict__ Qb, const u16* __restrict__ Kb,
    const u16* __restrict__ AVt, const u16* __restrict__ AVq,
    const float* __restrict__ Mrow, const float* __restrict__ Lrow,
    u16* __restrict__ TW) {
  __shared__ __align__(16) u16 Ks[64][72];
  __shared__ __align__(16) u16 Vs[64][72];
  __shared__ __align__(16) u16 Ps[64][72];
  const int tid = threadIdx.x, wave = tid >> 6, lane = tid & 63;
  const int f15 = lane & 15, quad = lane >> 4;
  const int y = blockIdx.y, b = y >> 4, h = y & 15;
  const int qt = (31 - (int)blockIdx.x + y) & 31;
  const int q0 = qt * 64;
  const size_t qk_base = ((size_t)h * NTOK + b * T_SEQ) * 64;
  const size_t vt_base = (size_t)h * 64 * NTOK + (size_t)b * T_SEQ;

  const int qrow = q0 + wave * 16 + f15;
  s16x8 qf0, qf1;
  {
    const u16* qp = Qb + qk_base + (size_t)qrow * 64 + quad * 8;
    qf0 = *reinterpret_cast<const s16x8*>(qp);
    qf1 = *reinterpret_cast<const s16x8*>(qp + 32);
  }
  const float m_r  = Mrow[(size_t)y * T_SEQ + qrow];
  const float invl = 1.0f / Lrow[(size_t)y * T_SEQ + qrow];
  f32x4 accO[4] = {};

  const int s_r = tid >> 3;
  const int s_c = (tid & 7) * 8;

  for (int ti = 0; ti <= qt; ti++) {
    const int j0 = ti * 64;
#pragma unroll
    for (int it = 0; it < 2; it++) {
      int r = it * 32 + s_r;
      *reinterpret_cast<u16x8*>(&Ks[r][s_c]) =
          *reinterpret_cast<const u16x8*>(Kb + qk_base + (size_t)(j0 + r) * 64 + s_c);
      *reinterpret_cast<u16x8*>(&Vs[r][s_c]) =
          *reinterpret_cast<const u16x8*>(AVt + vt_base + (size_t)r * NTOK + j0 + s_c);
    }
    __syncthreads();

    f32x4 accS[4] = {};
#pragma unroll
    for (int nt = 0; nt < 4; nt++) {
      s16x8 ak0 = *reinterpret_cast<const s16x8*>(&Ks[nt * 16 + f15][quad * 8]);
      accS[nt] = __builtin_amdgcn_mfma_f32_16x16x32_bf16(ak0, qf0, accS[nt], 0, 0, 0);
      s16x8 ak1 = *reinterpret_cast<const s16x8*>(&Ks[nt * 16 + f15][32 + quad * 8]);
      accS[nt] = __builtin_amdgcn_mfma_f32_16x16x32_bf16(ak1, qf1, accS[nt], 0, 0, 0);
    }
    if (ti == qt) {
#pragma unroll
      for (int nt = 0; nt < 4; nt++)
#pragma unroll
        for (int r = 0; r < 4; r++)
          if (j0 + nt * 16 + quad * 4 + r > qrow) accS[nt][r] = -3.0e38f;
    }
#pragma unroll
    for (int nt = 0; nt < 4; nt++) {
      float p0 = __builtin_amdgcn_exp2f(accS[nt][0] - m_r);
      float p1 = __builtin_amdgcn_exp2f(accS[nt][1] - m_r);
      float p2 = __builtin_amdgcn_exp2f(accS[nt][2] - m_r);
      float p3 = __builtin_amdgcn_exp2f(accS[nt][3] - m_r);
      uint2 w; w.x = pk2(p0, p1); w.y = pk2(p2, p3);
      *reinterpret_cast<uint2*>(&Ps[wave * 16 + f15][nt * 16 + quad * 4]) = w;
    }
#pragma unroll
    for (int ks = 0; ks < 2; ks++) {
      s16x8 bp = *reinterpret_cast<const s16x8*>(&Ps[wave * 16 + f15][ks * 32 + quad * 8]);
#pragma unroll
      for (int nt = 0; nt < 4; nt++) {
        s16x8 av = *reinterpret_cast<const s16x8*>(&Vs[nt * 16 + f15][ks * 32 + quad * 8]);
        accO[nt] = __builtin_amdgcn_mfma_f32_16x16x32_bf16(av, bp, accO[nt], 0, 0, 0);
      }
    }
    __syncthreads();
  }

  // stage AAV as [q][d] tile, then fused tw = 2*AV - AAV copy-out
#pragma unroll
  for (int nt = 0; nt < 4; nt++) {
    uint2 w;
    w.x = pk2(accO[nt][0] * invl, accO[nt][1] * invl);
    w.y = pk2(accO[nt][2] * invl, accO[nt][3] * invl);
    *reinterpret_cast<uint2*>(&Vs[wave * 16 + f15][nt * 16 + quad * 4]) = w;
  }
  __syncthreads();
#pragma unroll
  for (int it = 0; it < 2; it++) {
    int r = it * 32 + s_r;
    u16x8 aav8 = *reinterpret_cast<const u16x8*>(&Vs[r][s_c]);
    u16x8 av8  = *reinterpret_cast<const u16x8*>(
        AVq + (size_t)(b * T_SEQ + q0 + r) * DMODEL + h * 64 + s_c);
    unsigned o[4];
#pragma unroll
    for (int t = 0; t < 4; t++) {
      float a0 = 2.0f * bf2f(av8[2 * t])     - bf2f(aav8[2 * t]);
      float a1 = 2.0f * bf2f(av8[2 * t + 1]) - bf2f(aav8[2 * t + 1]);
      o[t] = pk2(a0, a1);
    }
    uint4 ov = make_uint4(o[0], o[1], o[2], o[3]);
    *reinterpret_cast<uint4*>(TW + (size_t)(b * T_SEQ + q0 + r) * DMODEL + h * 64 + s_c) = ov;
  }
}

// ---------------- launch ----------------
extern "C" void kernel_launch(void* const* d_in, const int* in_sizes, int n_in,
                              void* d_out, int out_size, void* d_ws, size_t ws_size,
                              hipStream_t stream) {
  const float* x    = (const float*)d_in[0];
  const float* Wqkv = (const float*)d_in[1];
  const float* Wout = (const float*)d_in[2];
  float* out = (float*)d_out;
  char* ws = (char*)d_ws;

  u16*   Xb    = (u16*)(ws + 0);           //  8 MB  4096x1024 bf16
  u16*   Wqkvb = (u16*)(ws + 8388608);     //  6 MB
  u16*   Woutb = (u16*)(ws + 14680064);    //  2 MB
  u16*   Qb    = (u16*)(ws + 16777216);    //  8 MB  [h][token][64] (pre-scaled, log2e folded)
  u16*   Kb    = (u16*)(ws + 25165824);    //  8 MB  [h][token][64]
  u16*   Vtb   = (u16*)(ws + 33554432);    //  8 MB  [h*64+d][token]
  u16*   TW    = (u16*)(ws + 41943040);    //  8 MB  [token][1024]
  u16*   AVt   = (u16*)(ws + 50331648);    //  8 MB  [h*64+d][token] bf16
  u16*   AVq   = (u16*)(ws + 58720256);    //  8 MB  [token][1024] bf16
  float* Mrow  = (float*)(ws + 67108864);  // 256 KB (log2 domain)
  float* Lrow  = (float*)(ws + 67371008);  // 256 KB

  cast_to_bf16<<<4096, 256, 0, stream>>>(x, Xb, 1048576);
  cast_to_bf16<<<3072, 256, 0, stream>>>(Wqkv, Wqkvb, 786432);
  cast_to_bf16<<<1024, 256, 0, stream>>>(Wout, Woutb, 262144);

  gemm_bf16_nt<0><<<dim3(64, 32), 256, 0, stream>>>(Xb, Wqkvb, NTOK, 2048, DMODEL,
                                                    Qb, Kb, nullptr, nullptr);
  gemm_bf16_nt<1><<<dim3(16, 64), 256, 0, stream>>>(Wqkvb + 2048 * 1024, Xb, 1024, NTOK, DMODEL,
                                                    nullptr, nullptr, Vtb, nullptr);

  attn_pass_a<<<dim3(32, 32), 256, 0, stream>>>(Qb, Kb, Vtb, AVt, AVq, Mrow, Lrow);
  attn_pass_b<<<dim3(32, 32), 256, 0, stream>>>(Qb, Kb, AVt, AVq, Mrow, Lrow, TW);

  gemm_bf16_nt<2><<<dim3(64, 16), 256, 0, stream>>>(TW, Woutb, NTOK, DMODEL, DMODEL,
                                                    nullptr, nullptr, nullptr, out);
}